// Round 2
// baseline (253.543 us; speedup 1.0000x reference)
//
#include <hip/hip_runtime.h>
#include <math.h>

// Problem constants (match reference)
#define NNODES 50000
#define NEDGES 800000
#define INF 128
#define OUTF 128
#define HEADS 2
#define NEG_SLOPE 0.2f

// Padded-bin CSR: degree ~ Poisson(16); CAP=32 overflows on ~1e-4 of nodes;
// overflow edges go to a small exact-path list.
#define CAP 32
#define OVFCAP 32768

__device__ __forceinline__ unsigned short f2bf(float f) {
    unsigned u = __float_as_uint(f);
    unsigned r = (u + 0x7FFFu + ((u >> 16) & 1u)) >> 16;   // RNE
    return (unsigned short)r;
}
__device__ __forceinline__ float bf2f(unsigned short b) {
    return __uint_as_float((unsigned)b << 16);
}

typedef __attribute__((ext_vector_type(8))) short frag_ab;   // 8 bf16 (4 VGPRs)
typedef __attribute__((ext_vector_type(4))) float frag_cd;   // 4 fp32 acc

// ---------- K0: init scratch + one-time param prep ----------
// blocks [0, cblk): zero cursor/ovfcnt
// block  cblk     : wfold[vq][128]  vq=0,1: attn_l-folded W per head; 2,3: attn_r
//                   one thread per (f,h); o-loop unrolled x16 for MLP.
// blocks cblk+1..cblk+8 : Wb = bf16(W)  (32768 elems)
__global__ void init_kernel(int* cursor, int* ovfcnt,
                            const float* __restrict__ W,
                            const float* __restrict__ attn_l,
                            const float* __restrict__ attn_r,
                            unsigned short* __restrict__ Wb,
                            float* __restrict__ wfold, int N) {
    const int b = blockIdx.x, t = threadIdx.x;
    const int cblk = (N + 255) >> 8;
    if (b < cblk) {
        int i = b * 256 + t;
        if (i < N) cursor[i] = 0;
        if (i == 0) *ovfcnt = 0;
        return;
    }
    if (b == cblk) {
        // el[n,h] = feat[n]·wfold[h], er[n,h] = feat[n]·wfold[2+h]
        int h = t >> 7, f = t & 127;
        float sl = 0.f, sr = 0.f;
#pragma unroll 16
        for (int o = 0; o < 128; ++o) {
            float wv = W[(size_t)(h * 128 + o) * 128 + f];
            sl = fmaf(attn_l[h * 128 + o], wv, sl);
            sr = fmaf(attn_r[h * 128 + o], wv, sr);
        }
        wfold[h * 128 + f] = sl;
        wfold[(2 + h) * 128 + f] = sr;
        return;
    }
    int base = (b - cblk - 1) * 4096 + t * 16;
#pragma unroll
    for (int q = 0; q < 4; ++q) {
        float4 g = *(const float4*)(W + base + q * 4);
        ushort4 v; v.x = f2bf(g.x); v.y = f2bf(g.y); v.z = f2bf(g.z); v.w = f2bf(g.w);
        *(ushort4*)(Wb + base + q * 4) = v;
    }
}

// ---------- K1: MFMA gemm, no LDS / no barriers ----------
// 4 waves/block, wave w owns node rows n0+w*16..+15. A frags: direct fp32 load
// from feat + in-register bf16 convert (each element converted once chip-wide).
// B frags: direct 16B loads from pre-converted Wb (L1/L2-hot, 64 KB).
// el/er computed as exact fp32 dots feat·wfold on the A registers.
// C/D layout (verified m89/m91): col=lane&15, row=(lane>>4)*4+reg.
__global__ __launch_bounds__(256) void gemm_mfma(const float* __restrict__ feat,
                                                 const unsigned short* __restrict__ Wb,
                                                 const float* __restrict__ wfold,
                                                 unsigned short* __restrict__ ftb,
                                                 float* __restrict__ el,
                                                 float* __restrict__ er,
                                                 int N) {
    const int t = threadIdx.x;
    const int w = t >> 6, lane = t & 63;
    const int m16 = lane & 15, quad = lane >> 4;
    const int n0 = blockIdx.x * 64;
    const int r = n0 + w * 16 + m16;      // this lane's A row
    const bool valid = r < N;

    frag_ab af[4];
    float pd[4] = {0.f, 0.f, 0.f, 0.f};   // wl0, wl1, wr0, wr1 partial dots
#pragma unroll
    for (int kc = 0; kc < 4; ++kc) {
        const int cc = kc * 32 + quad * 8;
        float4 g0 = make_float4(0.f, 0.f, 0.f, 0.f), g1 = g0;
        if (valid) {
            g0 = *(const float4*)(feat + (size_t)r * INF + cc);
            g1 = *(const float4*)(feat + (size_t)r * INF + cc + 4);
        }
        frag_ab a;
        a[0] = (short)f2bf(g0.x); a[1] = (short)f2bf(g0.y);
        a[2] = (short)f2bf(g0.z); a[3] = (short)f2bf(g0.w);
        a[4] = (short)f2bf(g1.x); a[5] = (short)f2bf(g1.y);
        a[6] = (short)f2bf(g1.z); a[7] = (short)f2bf(g1.w);
        af[kc] = a;
#pragma unroll
        for (int vq = 0; vq < 4; ++vq) {
            float4 w0 = *(const float4*)(wfold + vq * 128 + cc);
            float4 w1 = *(const float4*)(wfold + vq * 128 + cc + 4);
            pd[vq] += g0.x * w0.x + g0.y * w0.y + g0.z * w0.z + g0.w * w0.w
                    + g1.x * w1.x + g1.y * w1.y + g1.z * w1.z + g1.w * w1.w;
        }
    }
    // lane's 32 cols are 1/4 of the row; reduce across the 4 quads (xor 16,32)
#pragma unroll
    for (int m = 16; m < 64; m <<= 1)
#pragma unroll
        for (int vq = 0; vq < 4; ++vq) pd[vq] += __shfl_xor(pd[vq], m, 64);
    if (valid && quad == 0) {
        *(float2*)(el + (size_t)r * 2) = make_float2(pd[0], pd[1]);
        *(float2*)(er + (size_t)r * 2) = make_float2(pd[2], pd[3]);
    }

#pragma unroll
    for (int jt = 0; jt < 4; ++jt) {
        frag_cd acc[4];
#pragma unroll
        for (int nt = 0; nt < 4; ++nt) acc[nt] = frag_cd{0.f, 0.f, 0.f, 0.f};
#pragma unroll
        for (int kc = 0; kc < 4; ++kc) {
#pragma unroll
            for (int nt = 0; nt < 4; ++nt) {
                frag_ab bf = *(const frag_ab*)(Wb + (size_t)(jt * 64 + nt * 16 + m16) * INF
                                               + kc * 32 + quad * 8);
                acc[nt] = __builtin_amdgcn_mfma_f32_16x16x32_bf16(af[kc], bf, acc[nt], 0, 0, 0);
            }
        }
#pragma unroll
        for (int nt = 0; nt < 4; ++nt) {
            const int gj = jt * 64 + nt * 16 + m16;       // global j (= h*128+o flat)
#pragma unroll
            for (int reg = 0; reg < 4; ++reg) {
                int gm = n0 + w * 16 + quad * 4 + reg;
                if (gm < N) ftb[(size_t)gm * 256 + gj] = f2bf(acc[nt][reg]);
            }
        }
    }
}

// ---------- K2: fused edge logits + leaky_relu + exp + padded-bin scatter ----------
// No segment-max (softmax shift-invariant; logits O(10), exp safe in fp32).
__global__ void edge_fused(const float* __restrict__ el, const float* __restrict__ er,
                           const float* __restrict__ e_w, const int* __restrict__ src,
                           const int* __restrict__ dst, const float* __restrict__ attn_ew,
                           int* __restrict__ cursor, int* __restrict__ ovfcnt,
                           uint2* __restrict__ edata, float4* __restrict__ ovf,
                           int E) {
    int e = blockIdx.x * 256 + threadIdx.x;
    if (e >= E) return;
    int s = src[e], d = dst[e];
    float2 ew2 = *(const float2*)(e_w + (size_t)e * 2);
    float2 elv = *(const float2*)(el + (size_t)s * 2);
    float2 erv = *(const float2*)(er + (size_t)d * 2);
    float v0 = elv.x + erv.x + ew2.x * attn_ew[0] + ew2.y * attn_ew[1];
    float v1 = elv.y + erv.y + ew2.x * attn_ew[2] + ew2.y * attn_ew[3];
    v0 = v0 >= 0.f ? v0 : NEG_SLOPE * v0;
    v1 = v1 >= 0.f ? v1 : NEG_SLOPE * v1;
    float ee0 = __expf(v0);
    float ee1 = __expf(v1);
    int pos = atomicAdd(cursor + d, 1);
    if (pos < CAP) {
        unsigned pk = ((unsigned)f2bf(ee1) << 16) | (unsigned)f2bf(ee0);
        edata[(size_t)d * CAP + pos] = make_uint2((unsigned)s, pk);
    } else {
        int o = atomicAdd(ovfcnt, 1);
        if (o < OVFCAP)
            ovf[o] = make_float4(__int_as_float(d), __int_as_float(s), ee0, ee1);
    }
}

// ---------- K3: wave-per-node gather-aggregate + normalize + residual + elu ----------
// Whole 32-record bin prefetched once (one uint2/lane); per-edge record is
// broadcast from the prefetched registers via __shfl (ds_bpermute, ~60cy) --
// removes the per-iteration L2 broadcast load from the critical chain while
// keeping everything in VGPRs (the round-1 readlane variant collapsed the
// register file to 12 VGPRs and serialized the gathers). Unroll 8 keeps 8
// independent 512B gathers in flight.
__global__ __launch_bounds__(256) void aggregate(const unsigned short* __restrict__ ftb,
                                                 const float* __restrict__ feat,
                                                 const uint2* __restrict__ edata,
                                                 const int* __restrict__ cursor,
                                                 const int* __restrict__ ovfcnt,
                                                 const float4* __restrict__ ovf,
                                                 float* __restrict__ out, int N) {
    const int t = threadIdx.x;
    const int w = t >> 6, l = t & 63;
    const int n = blockIdx.x * 4 + w;
    if (n >= N) return;
    const int c0 = 4 * l;            // this lane's 4 cols (0..252)
    const int h = l >> 5;            // lane's head
    const int cnt = cursor[n];
    const int cmain = cnt < CAP ? cnt : CAP;
    const uint2* eb = edata + (size_t)n * CAP;
    const uint2 myrec = eb[l & 31];  // prefetch whole bin; recs >= cmain unused

    float4 acc = make_float4(0.f, 0.f, 0.f, 0.f);
    float dn = 0.f;
#pragma unroll 8
    for (int i = 0; i < cmain; ++i) {
        int sx = __shfl((int)myrec.x, i, 64);
        unsigned pk = (unsigned)__shfl((int)myrec.y, i, 64);
        float a = bf2f((unsigned short)(h ? (pk >> 16) : (pk & 0xFFFFu)));
        const ushort4 v = *(const ushort4*)(ftb + (size_t)(unsigned)sx * 256 + c0);
        dn += a;
        acc.x = fmaf(a, bf2f(v.x), acc.x);
        acc.y = fmaf(a, bf2f(v.y), acc.y);
        acc.z = fmaf(a, bf2f(v.z), acc.z);
        acc.w = fmaf(a, bf2f(v.w), acc.w);
    }
    if (cnt > CAP) {   // exact overflow path (rare)
        int no = *ovfcnt; if (no > OVFCAP) no = OVFCAP;
        for (int i = 0; i < no; ++i) {
            float4 ov = ovf[i];
            if (__float_as_int(ov.x) == n) {
                int s = __float_as_int(ov.y);
                float a = h ? ov.w : ov.z;
                dn += a;
                const ushort4 v = *(const ushort4*)(ftb + (size_t)s * 256 + c0);
                acc.x = fmaf(a, bf2f(v.x), acc.x);
                acc.y = fmaf(a, bf2f(v.y), acc.y);
                acc.z = fmaf(a, bf2f(v.z), acc.z);
                acc.w = fmaf(a, bf2f(v.w), acc.w);
            }
        }
    }
    float inv = dn > 0.f ? 1.0f / dn : 0.f;
    float4 f4 = *(const float4*)(feat + (size_t)n * INF + (c0 & 127));
    float4 r;
    r.x = acc.x * inv + f4.x;
    r.y = acc.y * inv + f4.y;
    r.z = acc.z * inv + f4.z;
    r.w = acc.w * inv + f4.w;
    r.x = r.x > 0.f ? r.x : expm1f(r.x);
    r.y = r.y > 0.f ? r.y : expm1f(r.y);
    r.z = r.z > 0.f ? r.z : expm1f(r.z);
    r.w = r.w > 0.f ? r.w : expm1f(r.w);
    *(float4*)(out + (size_t)n * 256 + c0) = r;
}

extern "C" void kernel_launch(void* const* d_in, const int* in_sizes, int n_in,
                              void* d_out, int out_size, void* d_ws, size_t ws_size,
                              hipStream_t stream) {
    const float* feat    = (const float*)d_in[0];
    const float* e_w     = (const float*)d_in[1];
    const int*   src     = (const int*)d_in[2];
    const int*   dst     = (const int*)d_in[3];
    const float* W       = (const float*)d_in[4];
    const float* attn_l  = (const float*)d_in[5];
    const float* attn_r  = (const float*)d_in[6];
    const float* attn_ew = (const float*)d_in[7];
    float* out = (float*)d_out;

    const int N = in_sizes[0] / INF;   // 50000
    const int E = in_sizes[2];         // 800000

    // workspace carve-up (all offsets 16B-aligned for these sizes)
    unsigned short* ftb = (unsigned short*)d_ws;                 // N*256 bf16   (25.6 MB)
    uint2*  edata  = (uint2*)(ftb + (size_t)N * 256);            // N*CAP        (12.8 MB)
    float*  el     = (float*)(edata + (size_t)N * CAP);          // N*2          (0.4 MB)
    float*  er     = el + (size_t)N * 2;                         // N*2          (0.4 MB)
    float*  wfold  = er + (size_t)N * 2;                         // 4*128 f      (2 KB)
    unsigned short* Wb = (unsigned short*)(wfold + 512);         // 256*128 bf16 (64 KB)
    float4* ovf    = (float4*)(Wb + 32768);                      // OVFCAP       (0.5 MB)
    int*    cursor = (int*)(ovf + OVFCAP);                       // N
    int*    ovfcnt = cursor + N;                                 // 1

    const int cblk = (N + 255) / 256;
    init_kernel<<<cblk + 9, 256, 0, stream>>>(cursor, ovfcnt, W, attn_l, attn_r, Wb, wfold, N);

    gemm_mfma<<<(N + 63) / 64, 256, 0, stream>>>(feat, Wb, wfold, ftb, el, er, N);

    edge_fused<<<(E + 255) / 256, 256, 0, stream>>>(el, er, e_w, src, dst, attn_ew,
                                                    cursor, ovfcnt, edata, ovf, E);

    aggregate<<<(N + 3) / 4, 256, 0, stream>>>(ftb, feat, edata, cursor, ovfcnt, ovf, out, N);
}

// Round 3
// 241.438 us; speedup vs baseline: 1.0501x; 1.0501x over previous
//
#include <hip/hip_runtime.h>
#include <math.h>

// Problem constants (match reference)
#define NNODES 50000
#define NEDGES 800000
#define INF 128
#define OUTF 128
#define HEADS 2
#define NEG_SLOPE 0.2f

// Padded-bin CSR: degree ~ Poisson(16); CAP=32 overflows on ~1e-4 of nodes;
// overflow edges go to a small exact-path list.
#define CAP 32
#define OVFCAP 32768

__device__ __forceinline__ unsigned short f2bf(float f) {
    unsigned u = __float_as_uint(f);
    unsigned r = (u + 0x7FFFu + ((u >> 16) & 1u)) >> 16;   // RNE
    return (unsigned short)r;
}
__device__ __forceinline__ float bf2f(unsigned short b) {
    return __uint_as_float((unsigned)b << 16);
}

typedef __attribute__((ext_vector_type(8))) short frag_ab;   // 8 bf16 (4 VGPRs)
typedef __attribute__((ext_vector_type(4))) float frag_cd;   // 4 fp32 acc
typedef __attribute__((ext_vector_type(8))) unsigned short ushort8v;

// ---------- K0: init scratch + one-time param prep ----------
// blocks [0, cblk): zero cursor/ovfcnt
// block  cblk     : wfold[vq][128]  vq=0,1: attn_l-folded W per head; 2,3: attn_r
//                   one thread per (f,h); o-loop unrolled x16 for MLP.
// blocks cblk+1..cblk+8 : Wb = bf16(W)  (32768 elems)
__global__ void init_kernel(int* cursor, int* ovfcnt,
                            const float* __restrict__ W,
                            const float* __restrict__ attn_l,
                            const float* __restrict__ attn_r,
                            unsigned short* __restrict__ Wb,
                            float* __restrict__ wfold, int N) {
    const int b = blockIdx.x, t = threadIdx.x;
    const int cblk = (N + 255) >> 8;
    if (b < cblk) {
        int i = b * 256 + t;
        if (i < N) cursor[i] = 0;
        if (i == 0) *ovfcnt = 0;
        return;
    }
    if (b == cblk) {
        // el[n,h] = feat[n]·wfold[h], er[n,h] = feat[n]·wfold[2+h]
        int h = t >> 7, f = t & 127;
        float sl = 0.f, sr = 0.f;
#pragma unroll 16
        for (int o = 0; o < 128; ++o) {
            float wv = W[(size_t)(h * 128 + o) * 128 + f];
            sl = fmaf(attn_l[h * 128 + o], wv, sl);
            sr = fmaf(attn_r[h * 128 + o], wv, sr);
        }
        wfold[h * 128 + f] = sl;
        wfold[(2 + h) * 128 + f] = sr;
        return;
    }
    int base = (b - cblk - 1) * 4096 + t * 16;
#pragma unroll
    for (int q = 0; q < 4; ++q) {
        float4 g = *(const float4*)(W + base + q * 4);
        ushort4 v; v.x = f2bf(g.x); v.y = f2bf(g.y); v.z = f2bf(g.z); v.w = f2bf(g.w);
        *(ushort4*)(Wb + base + q * 4) = v;
    }
}

// ---------- K1: MFMA gemm, no LDS / no barriers ----------
// 4 waves/block, wave w owns node rows n0+w*16..+15. A frags: direct fp32 load
// from feat + in-register bf16 convert. B frags: per j-tile, ALL 16 fragments
// are loaded into a static-indexed register array BEFORE the 16 MFMAs -- one
// batched vmcnt window per jt instead of a per-MFMA L2-latency wait (the
// round-1/2 regression: compiler interleaved load;mfma;load;mfma).
// el/er computed as exact fp32 dots feat·wfold on the A registers.
// C/D layout (verified m89/m91): col=lane&15, row=(lane>>4)*4+reg.
__global__ __launch_bounds__(256) void gemm_mfma(const float* __restrict__ feat,
                                                 const unsigned short* __restrict__ Wb,
                                                 const float* __restrict__ wfold,
                                                 unsigned short* __restrict__ ftb,
                                                 float* __restrict__ el,
                                                 float* __restrict__ er,
                                                 int N) {
    const int t = threadIdx.x;
    const int w = t >> 6, lane = t & 63;
    const int m16 = lane & 15, quad = lane >> 4;
    const int n0 = blockIdx.x * 64;
    const int r = n0 + w * 16 + m16;      // this lane's A row
    const bool valid = r < N;

    frag_ab af[4];
    float pd[4] = {0.f, 0.f, 0.f, 0.f};   // wl0, wl1, wr0, wr1 partial dots
#pragma unroll
    for (int kc = 0; kc < 4; ++kc) {
        const int cc = kc * 32 + quad * 8;
        float4 g0 = make_float4(0.f, 0.f, 0.f, 0.f), g1 = g0;
        if (valid) {
            g0 = *(const float4*)(feat + (size_t)r * INF + cc);
            g1 = *(const float4*)(feat + (size_t)r * INF + cc + 4);
        }
        frag_ab a;
        a[0] = (short)f2bf(g0.x); a[1] = (short)f2bf(g0.y);
        a[2] = (short)f2bf(g0.z); a[3] = (short)f2bf(g0.w);
        a[4] = (short)f2bf(g1.x); a[5] = (short)f2bf(g1.y);
        a[6] = (short)f2bf(g1.z); a[7] = (short)f2bf(g1.w);
        af[kc] = a;
#pragma unroll
        for (int vq = 0; vq < 4; ++vq) {
            float4 w0 = *(const float4*)(wfold + vq * 128 + cc);
            float4 w1 = *(const float4*)(wfold + vq * 128 + cc + 4);
            pd[vq] += g0.x * w0.x + g0.y * w0.y + g0.z * w0.z + g0.w * w0.w
                    + g1.x * w1.x + g1.y * w1.y + g1.z * w1.z + g1.w * w1.w;
        }
    }
    // lane's 32 cols are 1/4 of the row; reduce across the 4 quads (xor 16,32)
#pragma unroll
    for (int m = 16; m < 64; m <<= 1)
#pragma unroll
        for (int vq = 0; vq < 4; ++vq) pd[vq] += __shfl_xor(pd[vq], m, 64);
    if (valid && quad == 0) {
        *(float2*)(el + (size_t)r * 2) = make_float2(pd[0], pd[1]);
        *(float2*)(er + (size_t)r * 2) = make_float2(pd[2], pd[3]);
    }

#pragma unroll 1
    for (int jt = 0; jt < 4; ++jt) {
        // batch-load all 16 B fragments of this j-tile (static indices -> regs)
        frag_ab bfr[16];
#pragma unroll
        for (int kc = 0; kc < 4; ++kc)
#pragma unroll
            for (int nt = 0; nt < 4; ++nt)
                bfr[kc * 4 + nt] = *(const frag_ab*)(Wb
                        + (size_t)(jt * 64 + nt * 16 + m16) * INF + kc * 32 + quad * 8);

        frag_cd acc[4];
#pragma unroll
        for (int nt = 0; nt < 4; ++nt) acc[nt] = frag_cd{0.f, 0.f, 0.f, 0.f};
#pragma unroll
        for (int kc = 0; kc < 4; ++kc)
#pragma unroll
            for (int nt = 0; nt < 4; ++nt)
                acc[nt] = __builtin_amdgcn_mfma_f32_16x16x32_bf16(af[kc], bfr[kc * 4 + nt],
                                                                  acc[nt], 0, 0, 0);
#pragma unroll
        for (int nt = 0; nt < 4; ++nt) {
            const int gj = jt * 64 + nt * 16 + m16;       // global j (= h*128+o flat)
#pragma unroll
            for (int reg = 0; reg < 4; ++reg) {
                int gm = n0 + w * 16 + quad * 4 + reg;
                if (gm < N) ftb[(size_t)gm * 256 + gj] = f2bf(acc[nt][reg]);
            }
        }
    }
}

// ---------- K2: fused edge logits + leaky_relu + exp + padded-bin scatter ----------
// No segment-max (softmax shift-invariant; logits O(10), exp safe in fp32).
__global__ void edge_fused(const float* __restrict__ el, const float* __restrict__ er,
                           const float* __restrict__ e_w, const int* __restrict__ src,
                           const int* __restrict__ dst, const float* __restrict__ attn_ew,
                           int* __restrict__ cursor, int* __restrict__ ovfcnt,
                           uint2* __restrict__ edata, float4* __restrict__ ovf,
                           int E) {
    int e = blockIdx.x * 256 + threadIdx.x;
    if (e >= E) return;
    int s = src[e], d = dst[e];
    float2 ew2 = *(const float2*)(e_w + (size_t)e * 2);
    float2 elv = *(const float2*)(el + (size_t)s * 2);
    float2 erv = *(const float2*)(er + (size_t)d * 2);
    float v0 = elv.x + erv.x + ew2.x * attn_ew[0] + ew2.y * attn_ew[1];
    float v1 = elv.y + erv.y + ew2.x * attn_ew[2] + ew2.y * attn_ew[3];
    v0 = v0 >= 0.f ? v0 : NEG_SLOPE * v0;
    v1 = v1 >= 0.f ? v1 : NEG_SLOPE * v1;
    float ee0 = __expf(v0);
    float ee1 = __expf(v1);
    int pos = atomicAdd(cursor + d, 1);
    if (pos < CAP) {
        unsigned pk = ((unsigned)f2bf(ee1) << 16) | (unsigned)f2bf(ee0);
        edata[(size_t)d * CAP + pos] = make_uint2((unsigned)s, pk);
    } else {
        int o = atomicAdd(ovfcnt, 1);
        if (o < OVFCAP)
            ovf[o] = make_float4(__int_as_float(d), __int_as_float(s), ee0, ee1);
    }
}

// ---------- K3: wave-per-node gather-aggregate + normalize + residual + elu ----------
// Half-wave edge split: half-lane hl covers 8 cols via one ushort8 (16B/lane,
// coalescing sweet spot); lower half takes even edges, upper half odd edges.
// Iterations per node halve (16->8) and in-flight gathers double at the same
// unroll. Records come from direct L1-hit broadcast loads (round-0-proven; the
// shfl-broadcast variant put a ds_bpermute in the address chain and regressed).
// One shfl_xor(32) combine at the end.
__global__ __launch_bounds__(256) void aggregate(const unsigned short* __restrict__ ftb,
                                                 const float* __restrict__ feat,
                                                 const uint2* __restrict__ edata,
                                                 const int* __restrict__ cursor,
                                                 const int* __restrict__ ovfcnt,
                                                 const float4* __restrict__ ovf,
                                                 float* __restrict__ out, int N) {
    const int t = threadIdx.x;
    const int w = t >> 6, l = t & 63;
    const int n = blockIdx.x * 4 + w;
    if (n >= N) return;
    const int hl = l & 31;           // half-lane id
    const int half = l >> 5;         // 0: even edges, 1: odd edges
    const int c8 = 8 * hl;           // 8-col base this half-lane covers
    const int h = hl >> 4;           // head for these cols
    const int cnt = cursor[n];
    const int cmain = cnt < CAP ? cnt : CAP;
    const uint2* eb = edata + (size_t)n * CAP;

    float4 a0 = make_float4(0.f, 0.f, 0.f, 0.f);
    float4 a1 = make_float4(0.f, 0.f, 0.f, 0.f);
    float dn = 0.f;
    const int hm = (cmain + 1) >> 1;
#pragma unroll 4
    for (int i = 0; i < hm; ++i) {
        const int j = 2 * i + half;
        const bool vld = j < cmain;
        uint2 rec = eb[vld ? j : 0];
        float aw = bf2f((unsigned short)(h ? (rec.y >> 16) : (rec.y & 0xFFFFu)));
        float a = vld ? aw : 0.f;
        unsigned su = vld ? rec.x : 0u;
        ushort8v v = *(const ushort8v*)(ftb + (size_t)su * 256 + c8);
        dn += a;
        a0.x = fmaf(a, bf2f(v[0]), a0.x);
        a0.y = fmaf(a, bf2f(v[1]), a0.y);
        a0.z = fmaf(a, bf2f(v[2]), a0.z);
        a0.w = fmaf(a, bf2f(v[3]), a0.w);
        a1.x = fmaf(a, bf2f(v[4]), a1.x);
        a1.y = fmaf(a, bf2f(v[5]), a1.y);
        a1.z = fmaf(a, bf2f(v[6]), a1.z);
        a1.w = fmaf(a, bf2f(v[7]), a1.w);
    }
    // combine even/odd halves (lanes l and l^32 cover the same 8 cols)
    a0.x += __shfl_xor(a0.x, 32, 64);
    a0.y += __shfl_xor(a0.y, 32, 64);
    a0.z += __shfl_xor(a0.z, 32, 64);
    a0.w += __shfl_xor(a0.w, 32, 64);
    a1.x += __shfl_xor(a1.x, 32, 64);
    a1.y += __shfl_xor(a1.y, 32, 64);
    a1.z += __shfl_xor(a1.z, 32, 64);
    a1.w += __shfl_xor(a1.w, 32, 64);
    dn += __shfl_xor(dn, 32, 64);

    if (cnt > CAP) {   // exact overflow path (rare); runs post-combine, all
        int no = *ovfcnt; if (no > OVFCAP) no = OVFCAP;   // lanes add identically
        for (int i = 0; i < no; ++i) {
            float4 ov = ovf[i];
            if (__float_as_int(ov.x) == n) {
                int s = __float_as_int(ov.y);
                float a = h ? ov.w : ov.z;
                dn += a;
                ushort8v v = *(const ushort8v*)(ftb + (size_t)s * 256 + c8);
                a0.x = fmaf(a, bf2f(v[0]), a0.x);
                a0.y = fmaf(a, bf2f(v[1]), a0.y);
                a0.z = fmaf(a, bf2f(v[2]), a0.z);
                a0.w = fmaf(a, bf2f(v[3]), a0.w);
                a1.x = fmaf(a, bf2f(v[4]), a1.x);
                a1.y = fmaf(a, bf2f(v[5]), a1.y);
                a1.z = fmaf(a, bf2f(v[6]), a1.z);
                a1.w = fmaf(a, bf2f(v[7]), a1.w);
            }
        }
    }
    float inv = dn > 0.f ? 1.0f / dn : 0.f;
    const int cb = c8 + 4 * half;            // this lane's 4 output cols
    float4 av = half ? a1 : a0;
    float4 f4 = *(const float4*)(feat + (size_t)n * INF + (cb & 127));
    float4 r;
    r.x = fmaf(av.x, inv, f4.x);
    r.y = fmaf(av.y, inv, f4.y);
    r.z = fmaf(av.z, inv, f4.z);
    r.w = fmaf(av.w, inv, f4.w);
    r.x = r.x > 0.f ? r.x : expm1f(r.x);
    r.y = r.y > 0.f ? r.y : expm1f(r.y);
    r.z = r.z > 0.f ? r.z : expm1f(r.z);
    r.w = r.w > 0.f ? r.w : expm1f(r.w);
    *(float4*)(out + (size_t)n * 256 + cb) = r;
}

extern "C" void kernel_launch(void* const* d_in, const int* in_sizes, int n_in,
                              void* d_out, int out_size, void* d_ws, size_t ws_size,
                              hipStream_t stream) {
    const float* feat    = (const float*)d_in[0];
    const float* e_w     = (const float*)d_in[1];
    const int*   src     = (const int*)d_in[2];
    const int*   dst     = (const int*)d_in[3];
    const float* W       = (const float*)d_in[4];
    const float* attn_l  = (const float*)d_in[5];
    const float* attn_r  = (const float*)d_in[6];
    const float* attn_ew = (const float*)d_in[7];
    float* out = (float*)d_out;

    const int N = in_sizes[0] / INF;   // 50000
    const int E = in_sizes[2];         // 800000

    // workspace carve-up (all offsets 16B-aligned for these sizes)
    unsigned short* ftb = (unsigned short*)d_ws;                 // N*256 bf16   (25.6 MB)
    uint2*  edata  = (uint2*)(ftb + (size_t)N * 256);            // N*CAP        (12.8 MB)
    float*  el     = (float*)(edata + (size_t)N * CAP);          // N*2          (0.4 MB)
    float*  er     = el + (size_t)N * 2;                         // N*2          (0.4 MB)
    float*  wfold  = er + (size_t)N * 2;                         // 4*128 f      (2 KB)
    unsigned short* Wb = (unsigned short*)(wfold + 512);         // 256*128 bf16 (64 KB)
    float4* ovf    = (float4*)(Wb + 32768);                      // OVFCAP       (0.5 MB)
    int*    cursor = (int*)(ovf + OVFCAP);                       // N
    int*    ovfcnt = cursor + N;                                 // 1

    const int cblk = (N + 255) / 256;
    init_kernel<<<cblk + 9, 256, 0, stream>>>(cursor, ovfcnt, W, attn_l, attn_r, Wb, wfold, N);

    gemm_mfma<<<(N + 63) / 64, 256, 0, stream>>>(feat, Wb, wfold, ftb, el, er, N);

    edge_fused<<<(E + 255) / 256, 256, 0, stream>>>(el, er, e_w, src, dst, attn_ew,
                                                    cursor, ovfcnt, edata, ovf, E);

    aggregate<<<(N + 3) / 4, 256, 0, stream>>>(ftb, feat, edata, cursor, ovfcnt, ovf, out, N);
}

// Round 4
// 224.580 us; speedup vs baseline: 1.1290x; 1.0751x over previous
//
#include <hip/hip_runtime.h>
#include <math.h>

// Problem constants (match reference)
#define NNODES 50000
#define NEDGES 800000
#define INF 128
#define OUTF 128
#define HEADS 2
#define NEG_SLOPE 0.2f

// Padded-bin CSR, 2-way sharded cursors: degree ~ Poisson(16) split ~8/8 over
// two shards of 16 slots each (same 32-record bin). Sharding halves the serial
// atomic chain per cache line (16 -> 8 RMWs avg) and the two cursors live in
// different lines (cursor[s*N+d]). An edge that finds its shard full retries
// the sibling; only both-full goes to the exact overflow list.
#define CAP 32
#define SCAP 16
#define OVFCAP 32768

__device__ __forceinline__ unsigned short f2bf(float f) {
    unsigned u = __float_as_uint(f);
    unsigned r = (u + 0x7FFFu + ((u >> 16) & 1u)) >> 16;   // RNE
    return (unsigned short)r;
}
__device__ __forceinline__ float bf2f(unsigned short b) {
    return __uint_as_float((unsigned)b << 16);
}

typedef __attribute__((ext_vector_type(8))) short frag_ab;   // 8 bf16 (4 VGPRs)
typedef __attribute__((ext_vector_type(4))) float frag_cd;   // 4 fp32 acc
typedef __attribute__((ext_vector_type(8))) unsigned short ushort8v;

#define APITCH 136   // halfs per padded LDS row (272 B)

// ---------- K0: init scratch + one-time param prep ----------
// blocks [0, czblk): zero 2N sharded cursors + ovfcnt
// block  czblk     : wfold[vq][128]  vq=0,1: attn_l-folded W per head; 2,3: attn_r
// blocks czblk+1..+8 : Wb = bf16(W)  (32768 elems)
__global__ void init_kernel(int* cursor, int* ovfcnt,
                            const float* __restrict__ W,
                            const float* __restrict__ attn_l,
                            const float* __restrict__ attn_r,
                            unsigned short* __restrict__ Wb,
                            float* __restrict__ wfold, int N) {
    const int b = blockIdx.x, t = threadIdx.x;
    const int czblk = (2 * N + 255) >> 8;
    if (b < czblk) {
        int i = b * 256 + t;
        if (i < 2 * N) cursor[i] = 0;
        if (i == 0) *ovfcnt = 0;
        return;
    }
    if (b == czblk) {
        // el[n,h] = feat[n]·wfold[h], er[n,h] = feat[n]·wfold[2+h]
        int h = t >> 7, f = t & 127;
        float sl = 0.f, sr = 0.f;
#pragma unroll 16
        for (int o = 0; o < 128; ++o) {
            float wv = W[(size_t)(h * 128 + o) * 128 + f];
            sl = fmaf(attn_l[h * 128 + o], wv, sl);
            sr = fmaf(attn_r[h * 128 + o], wv, sr);
        }
        wfold[h * 128 + f] = sl;
        wfold[(2 + h) * 128 + f] = sr;
        return;
    }
    int base = (b - czblk - 1) * 4096 + t * 16;
#pragma unroll
    for (int q = 0; q < 4; ++q) {
        float4 g = *(const float4*)(W + base + q * 4);
        ushort4 v; v.x = f2bf(g.x); v.y = f2bf(g.y); v.z = f2bf(g.z); v.w = f2bf(g.w);
        *(ushort4*)(Wb + base + q * 4) = v;
    }
}

// ---------- K1: MFMA gemm, one-shot LDS-staged B ----------
// The whole 64 KB Wb is staged to LDS once per block (padded APITCH -> at most
// 2-way bank aliasing on frag reads, which is free). This removes the rounds
// 1-3 pathology where every wave streamed 256 KB of Wb through a 32 KB L1
// (4 L2-latency windows per wave with ~4 waves/SIMD to hide them).
// A frags: direct fp32 load from feat + in-register bf16 convert.
// el/er computed as exact fp32 dots feat·wfold on the A registers.
// C/D layout (verified m89/m91): col=lane&15, row=(lane>>4)*4+reg.
__global__ __launch_bounds__(256) void gemm_mfma(const float* __restrict__ feat,
                                                 const unsigned short* __restrict__ Wb,
                                                 const float* __restrict__ wfold,
                                                 unsigned short* __restrict__ ftb,
                                                 float* __restrict__ el,
                                                 float* __restrict__ er,
                                                 int N) {
    __shared__ unsigned short Bs[256 * APITCH];   // 69,632 B -> 2 blocks/CU
    const int t = threadIdx.x;
    const int w = t >> 6, lane = t & 63;
    const int m16 = lane & 15, quad = lane >> 4;
    const int n0 = blockIdx.x * 64;
    const int r = n0 + w * 16 + m16;      // this lane's A row
    const bool valid = r < N;

    // stage Wb -> Bs, coalesced: 4096 16B-chunks, 16 per thread
#pragma unroll
    for (int i = 0; i < 16; ++i) {
        int q = t + i * 256;             // chunk id 0..4095
        int row = q >> 4, c = q & 15;    // row 0..255, 16B chunk 0..15
        ushort8v v = *(const ushort8v*)(Wb + row * 128 + c * 8);
        *(ushort8v*)(&Bs[row * APITCH + c * 8]) = v;
    }

    frag_ab af[4];
    float pd[4] = {0.f, 0.f, 0.f, 0.f};   // wl0, wl1, wr0, wr1 partial dots
#pragma unroll
    for (int kc = 0; kc < 4; ++kc) {
        const int cc = kc * 32 + quad * 8;
        float4 g0 = make_float4(0.f, 0.f, 0.f, 0.f), g1 = g0;
        if (valid) {
            g0 = *(const float4*)(feat + (size_t)r * INF + cc);
            g1 = *(const float4*)(feat + (size_t)r * INF + cc + 4);
        }
        frag_ab a;
        a[0] = (short)f2bf(g0.x); a[1] = (short)f2bf(g0.y);
        a[2] = (short)f2bf(g0.z); a[3] = (short)f2bf(g0.w);
        a[4] = (short)f2bf(g1.x); a[5] = (short)f2bf(g1.y);
        a[6] = (short)f2bf(g1.z); a[7] = (short)f2bf(g1.w);
        af[kc] = a;
#pragma unroll
        for (int vq = 0; vq < 4; ++vq) {
            float4 w0 = *(const float4*)(wfold + vq * 128 + cc);
            float4 w1 = *(const float4*)(wfold + vq * 128 + cc + 4);
            pd[vq] += g0.x * w0.x + g0.y * w0.y + g0.z * w0.z + g0.w * w0.w
                    + g1.x * w1.x + g1.y * w1.y + g1.z * w1.z + g1.w * w1.w;
        }
    }
    // lane's 32 cols are 1/4 of the row; reduce across the 4 quads (xor 16,32)
#pragma unroll
    for (int m = 16; m < 64; m <<= 1)
#pragma unroll
        for (int vq = 0; vq < 4; ++vq) pd[vq] += __shfl_xor(pd[vq], m, 64);
    if (valid && quad == 0) {
        *(float2*)(el + (size_t)r * 2) = make_float2(pd[0], pd[1]);
        *(float2*)(er + (size_t)r * 2) = make_float2(pd[2], pd[3]);
    }

    __syncthreads();   // Bs ready

#pragma unroll
    for (int jt = 0; jt < 4; ++jt) {
        frag_cd acc[4];
#pragma unroll
        for (int nt = 0; nt < 4; ++nt) acc[nt] = frag_cd{0.f, 0.f, 0.f, 0.f};
#pragma unroll
        for (int kc = 0; kc < 4; ++kc)
#pragma unroll
            for (int nt = 0; nt < 4; ++nt) {
                frag_ab bf = *(const frag_ab*)(&Bs[(jt * 64 + nt * 16 + m16) * APITCH
                                                   + kc * 32 + quad * 8]);
                acc[nt] = __builtin_amdgcn_mfma_f32_16x16x32_bf16(af[kc], bf, acc[nt], 0, 0, 0);
            }
#pragma unroll
        for (int nt = 0; nt < 4; ++nt) {
            const int gj = jt * 64 + nt * 16 + m16;       // global j (= h*128+o flat)
#pragma unroll
            for (int reg = 0; reg < 4; ++reg) {
                int gm = n0 + w * 16 + quad * 4 + reg;
                if (gm < N) ftb[(size_t)gm * 256 + gj] = f2bf(acc[nt][reg]);
            }
        }
    }
}

// ---------- K2: fused edge logits + leaky_relu + exp + sharded-bin scatter ----------
// No segment-max (softmax shift-invariant; logits O(10), exp safe in fp32).
__global__ void edge_fused(const float* __restrict__ el, const float* __restrict__ er,
                           const float* __restrict__ e_w, const int* __restrict__ src,
                           const int* __restrict__ dst, const float* __restrict__ attn_ew,
                           int* __restrict__ cursor, int* __restrict__ ovfcnt,
                           uint2* __restrict__ edata, float4* __restrict__ ovf,
                           int N, int E) {
    int e = blockIdx.x * 256 + threadIdx.x;
    if (e >= E) return;
    int s = src[e], d = dst[e];
    float2 ew2 = *(const float2*)(e_w + (size_t)e * 2);
    float2 elv = *(const float2*)(el + (size_t)s * 2);
    float2 erv = *(const float2*)(er + (size_t)d * 2);
    float v0 = elv.x + erv.x + ew2.x * attn_ew[0] + ew2.y * attn_ew[1];
    float v1 = elv.y + erv.y + ew2.x * attn_ew[2] + ew2.y * attn_ew[3];
    v0 = v0 >= 0.f ? v0 : NEG_SLOPE * v0;
    v1 = v1 >= 0.f ? v1 : NEG_SLOPE * v1;
    float ee0 = __expf(v0);
    float ee1 = __expf(v1);
    unsigned pk = ((unsigned)f2bf(ee1) << 16) | (unsigned)f2bf(ee0);
    uint2 rec = make_uint2((unsigned)s, pk);
    uint2* bin = edata + (size_t)d * CAP;
    int sh = e & 1;
    int pos = atomicAdd(cursor + (size_t)sh * N + d, 1);
    if (pos < SCAP) {
        bin[sh * SCAP + pos] = rec;
    } else {
        sh ^= 1;                           // retry sibling shard
        int pos2 = atomicAdd(cursor + (size_t)sh * N + d, 1);
        if (pos2 < SCAP) {
            bin[sh * SCAP + pos2] = rec;
        } else {
            int o = atomicAdd(ovfcnt, 1);
            if (o < OVFCAP)
                ovf[o] = make_float4(__int_as_float(d), __int_as_float(s), ee0, ee1);
        }
    }
}

// ---------- K3: wave-per-node gather-aggregate + normalize + residual + elu ----------
// Half-wave edge split (hl covers 8 cols via one ushort8; lower half even edges,
// upper half odd) + unroll 8: the whole avg-degree-16 node is software-pipelined
// (8 record loads then 8 512B gathers in flight). Records via direct broadcast
// loads (L1-hot bin; shfl/readlane in the address chain regressed, r1/r2).
// Sharded bin: valid records are prefixes [0,cnt0) and [16,16+cnt1).
__global__ __launch_bounds__(256) void aggregate(const unsigned short* __restrict__ ftb,
                                                 const float* __restrict__ feat,
                                                 const uint2* __restrict__ edata,
                                                 const int* __restrict__ cursor,
                                                 const int* __restrict__ ovfcnt,
                                                 const float4* __restrict__ ovf,
                                                 float* __restrict__ out, int N) {
    const int t = threadIdx.x;
    const int w = t >> 6, l = t & 63;
    const int n = blockIdx.x * 4 + w;
    if (n >= N) return;
    const int hl = l & 31;           // half-lane id
    const int half = l >> 5;         // 0: even edges, 1: odd edges
    const int c8 = 8 * hl;           // 8-col base this half-lane covers
    const int h = hl >> 4;           // head for these cols
    const int c0c = cursor[n], c1c = cursor[N + n];
    const int cnt0 = c0c < SCAP ? c0c : SCAP;
    const int cnt1 = c1c < SCAP ? c1c : SCAP;
    const int cnt = cnt0 + cnt1;
    const uint2* eb = edata + (size_t)n * CAP;

    float4 a0 = make_float4(0.f, 0.f, 0.f, 0.f);
    float4 a1 = make_float4(0.f, 0.f, 0.f, 0.f);
    float dn = 0.f;
    const int hm = (cnt + 1) >> 1;
#pragma unroll 8
    for (int i = 0; i < hm; ++i) {
        const int j = 2 * i + half;
        const bool vld = j < cnt;
        const int jj = j < cnt0 ? j : j - cnt0 + SCAP;   // skip shard-0 pad slots
        uint2 rec = eb[vld ? jj : 0];
        float aw = bf2f((unsigned short)(h ? (rec.y >> 16) : (rec.y & 0xFFFFu)));
        float a = vld ? aw : 0.f;
        unsigned su = vld ? rec.x : 0u;
        ushort8v v = *(const ushort8v*)(ftb + (size_t)su * 256 + c8);
        dn += a;
        a0.x = fmaf(a, bf2f(v[0]), a0.x);
        a0.y = fmaf(a, bf2f(v[1]), a0.y);
        a0.z = fmaf(a, bf2f(v[2]), a0.z);
        a0.w = fmaf(a, bf2f(v[3]), a0.w);
        a1.x = fmaf(a, bf2f(v[4]), a1.x);
        a1.y = fmaf(a, bf2f(v[5]), a1.y);
        a1.z = fmaf(a, bf2f(v[6]), a1.z);
        a1.w = fmaf(a, bf2f(v[7]), a1.w);
    }
    // combine even/odd halves (lanes l and l^32 cover the same 8 cols)
    a0.x += __shfl_xor(a0.x, 32, 64);
    a0.y += __shfl_xor(a0.y, 32, 64);
    a0.z += __shfl_xor(a0.z, 32, 64);
    a0.w += __shfl_xor(a0.w, 32, 64);
    a1.x += __shfl_xor(a1.x, 32, 64);
    a1.y += __shfl_xor(a1.y, 32, 64);
    a1.z += __shfl_xor(a1.z, 32, 64);
    a1.w += __shfl_xor(a1.w, 32, 64);
    dn += __shfl_xor(dn, 32, 64);

    if (c0c > SCAP && c1c > SCAP) {   // both shards overflowed -> exact path
        int no = *ovfcnt; if (no > OVFCAP) no = OVFCAP;   // all lanes add identically
        for (int i = 0; i < no; ++i) {
            float4 ov = ovf[i];
            if (__float_as_int(ov.x) == n) {
                int s = __float_as_int(ov.y);
                float a = h ? ov.w : ov.z;
                dn += a;
                ushort8v v = *(const ushort8v*)(ftb + (size_t)s * 256 + c8);
                a0.x = fmaf(a, bf2f(v[0]), a0.x);
                a0.y = fmaf(a, bf2f(v[1]), a0.y);
                a0.z = fmaf(a, bf2f(v[2]), a0.z);
                a0.w = fmaf(a, bf2f(v[3]), a0.w);
                a1.x = fmaf(a, bf2f(v[4]), a1.x);
                a1.y = fmaf(a, bf2f(v[5]), a1.y);
                a1.z = fmaf(a, bf2f(v[6]), a1.z);
                a1.w = fmaf(a, bf2f(v[7]), a1.w);
            }
        }
    }
    float inv = dn > 0.f ? 1.0f / dn : 0.f;
    const int cb = c8 + 4 * half;            // this lane's 4 output cols
    float4 av = half ? a1 : a0;
    float4 f4 = *(const float4*)(feat + (size_t)n * INF + (cb & 127));
    float4 r;
    r.x = fmaf(av.x, inv, f4.x);
    r.y = fmaf(av.y, inv, f4.y);
    r.z = fmaf(av.z, inv, f4.z);
    r.w = fmaf(av.w, inv, f4.w);
    r.x = r.x > 0.f ? r.x : expm1f(r.x);
    r.y = r.y > 0.f ? r.y : expm1f(r.y);
    r.z = r.z > 0.f ? r.z : expm1f(r.z);
    r.w = r.w > 0.f ? r.w : expm1f(r.w);
    *(float4*)(out + (size_t)n * 256 + cb) = r;
}

extern "C" void kernel_launch(void* const* d_in, const int* in_sizes, int n_in,
                              void* d_out, int out_size, void* d_ws, size_t ws_size,
                              hipStream_t stream) {
    const float* feat    = (const float*)d_in[0];
    const float* e_w     = (const float*)d_in[1];
    const int*   src     = (const int*)d_in[2];
    const int*   dst     = (const int*)d_in[3];
    const float* W       = (const float*)d_in[4];
    const float* attn_l  = (const float*)d_in[5];
    const float* attn_r  = (const float*)d_in[6];
    const float* attn_ew = (const float*)d_in[7];
    float* out = (float*)d_out;

    const int N = in_sizes[0] / INF;   // 50000
    const int E = in_sizes[2];         // 800000

    // workspace carve-up (all offsets 16B-aligned for these sizes)
    unsigned short* ftb = (unsigned short*)d_ws;                 // N*256 bf16   (25.6 MB)
    uint2*  edata  = (uint2*)(ftb + (size_t)N * 256);            // N*CAP        (12.8 MB)
    float*  el     = (float*)(edata + (size_t)N * CAP);          // N*2          (0.4 MB)
    float*  er     = el + (size_t)N * 2;                         // N*2          (0.4 MB)
    float*  wfold  = er + (size_t)N * 2;                         // 4*128 f      (2 KB)
    unsigned short* Wb = (unsigned short*)(wfold + 512);         // 256*128 bf16 (64 KB)
    float4* ovf    = (float4*)(Wb + 32768);                      // OVFCAP       (0.5 MB)
    int*    cursor = (int*)(ovf + OVFCAP);                       // 2N (sharded)
    int*    ovfcnt = cursor + 2 * (size_t)N;                     // 1

    const int czblk = (2 * N + 255) / 256;
    init_kernel<<<czblk + 9, 256, 0, stream>>>(cursor, ovfcnt, W, attn_l, attn_r, Wb, wfold, N);

    gemm_mfma<<<(N + 63) / 64, 256, 0, stream>>>(feat, Wb, wfold, ftb, el, er, N);

    edge_fused<<<(E + 255) / 256, 256, 0, stream>>>(el, er, e_w, src, dst, attn_ew,
                                                    cursor, ovfcnt, edata, ovf, N, E);

    aggregate<<<(N + 3) / 4, 256, 0, stream>>>(ftb, feat, edata, cursor, ovfcnt, ovf, out, N);
}